// Round 6
// baseline (137.829 us; speedup 1.0000x reference)
//
#include <hip/hip_runtime.h>
#include <math.h>

#define CC 1024
#define SS 16
#define DD 512
#define RR (CC*SS)
#define EPSV 1e-8f
#define LDB 520    // B-tile row stride (shorts): bank-floor b128 reads
#define LDX 516    // k_pre LDS row stride (floats)
#define CHUNK 32   // cols per double-buffer half: 2*32*520*2 = 66.5 KB
#define NCHUNK 16  // 512 cols / 32

typedef __attribute__((ext_vector_type(8))) short short8;
typedef __attribute__((ext_vector_type(4))) float f32x4;
typedef unsigned short ushort_t;

__device__ __forceinline__ unsigned short f2bf(float f) {
  unsigned u = __float_as_uint(f);
  u += 0x7fffu + ((u >> 16) & 1u);  // RNE
  return (unsigned short)(u >> 16);
}

__device__ __forceinline__ void async16(void* l, const void* g) {
  __builtin_amdgcn_global_load_lds(
      (const __attribute__((address_space(1))) void*)g,
      (__attribute__((address_space(3))) void*)l, 16, 0, 0);
}

__device__ __forceinline__ float softplusf(float v) {
  return (v > 20.f) ? v : log1pf(expf(v));
}

#define SBAR()   __builtin_amdgcn_s_barrier()
#define SCHED0() __builtin_amdgcn_sched_barrier(0)

// ---------------- Kernel 1: per-class precompute ----------------
// xn written in MFMA-FRAGMENT ORDER: 16B units [class][kc][quad][cL];
// k_gemm loads each A-fragment as ONE coalesced 1KB wave read.
__global__ __launch_bounds__(256) void k_pre(
    const float* __restrict__ x, ushort_t* __restrict__ mn,
    float* __restrict__ nx, float* __restrict__ simpos,
    ushort_t* __restrict__ xn) {
  __shared__ float xs[SS * LDX];
  __shared__ float sums[DD];
  __shared__ float red[4];
  __shared__ float snm;
  __shared__ float rinv[SS];
  const int j = blockIdx.x, tid = threadIdx.x;
  const int wid = tid >> 6, lane = tid & 63;
  const float4* xj = (const float4*)(x + (size_t)j * SS * DD);
#pragma unroll
  for (int t = 0; t < 8; ++t) {
    const int idx = tid + t * 256;          // 2048 float4 units
    const int row = idx >> 7, d4 = idx & 127;
    *(float4*)(xs + row * LDX + d4 * 4) = xj[idx];
  }
  __syncthreads();

  // column sums (each thread owns a float2 column pair, kept in regs)
  float sx = 0.f, sy = 0.f;
#pragma unroll
  for (int i = 0; i < SS; ++i) {
    float2 v = *(const float2*)(xs + i * LDX + tid * 2);
    sx += v.x; sy += v.y;
  }
  ((float2*)sums)[tid] = make_float2(sx, sy);
  const float mxs = sx * (1.0f / SS), mys = sy * (1.0f / SS);
  float m2 = mxs * mxs + mys * mys;
#pragma unroll
  for (int off = 32; off > 0; off >>= 1) m2 += __shfl_xor(m2, off, 64);
  if (lane == 0) red[wid] = m2;
  __syncthreads();
  if (tid == 0) snm = sqrtf(red[0] + red[1] + red[2] + red[3]);
  __syncthreads();
  const float inm = (1.0f / SS) / snm;
  {
    unsigned lo = f2bf(sx * inm), hi = f2bf(sy * inm);
    ((unsigned*)(mn + (size_t)j * DD))[tid] = lo | (hi << 16);
  }

  // per-row norms: one 16-lane group per row, all 16 rows parallel
  {
    const int g = tid >> 4, l16 = tid & 15;
    float nx2 = 0.f, dxs = 0.f, t2 = 0.f;
    const float2* xr2 = (const float2*)(xs + g * LDX);
    const float2* sm2 = (const float2*)sums;
#pragma unroll
    for (int t = 0; t < 16; ++t) {
      float2 xv = xr2[l16 + t * 16];
      float2 sc = sm2[l16 + t * 16];
      nx2 = fmaf(xv.x, xv.x, fmaf(xv.y, xv.y, nx2));
      dxs = fmaf(xv.x, sc.x, fmaf(xv.y, sc.y, dxs));
      float tx = sc.x - xv.x, ty = sc.y - xv.y;
      t2 = fmaf(tx, tx, fmaf(ty, ty, t2));
    }
#pragma unroll
    for (int off = 1; off < 16; off <<= 1) {
      nx2 += __shfl_xor(nx2, off, 64);
      dxs += __shfl_xor(dxs, off, 64);
      t2  += __shfl_xor(t2,  off, 64);
    }
    if (l16 == 0) {
      float nxv = sqrtf(nx2);
      float tn  = sqrtf(t2);
      float num = (dxs - nx2) * (1.0f / (SS - 1));
      float den = fmaxf(nxv * tn * (1.0f / (SS - 1)), EPSV);
      nx[j * SS + g] = nxv;
      rinv[g] = 1.0f / nxv;
      simpos[j * SS + g] = num / den;
    }
  }
  __syncthreads();
  if (xn) {
    uint4* dst = (uint4*)xn + (size_t)j * 1024;  // 1024 16B units per class
#pragma unroll
    for (int t = 0; t < 4; ++t) {
      const int idxu = tid + t * 256;
      const int kc = idxu >> 6, quad = (idxu >> 4) & 3, cL = idxu & 15;
      const float* s = xs + cL * LDX + kc * 32 + quad * 8;
      const float4 a = *(const float4*)s;
      const float4 b2 = *(const float4*)(s + 4);
      const float ri = rinv[cL];
      uint4 o;
      o.x = (unsigned)f2bf(a.x * ri) | ((unsigned)f2bf(a.y * ri) << 16);
      o.y = (unsigned)f2bf(a.z * ri) | ((unsigned)f2bf(a.w * ri) << 16);
      o.z = (unsigned)f2bf(b2.x * ri) | ((unsigned)f2bf(b2.y * ri) << 16);
      o.w = (unsigned)f2bf(b2.z * ri) | ((unsigned)f2bf(b2.w * ri) << 16);
      dst[idxu] = o;
    }
  }
}

// ---------------- Kernel 2: MFMA GEMM + fused exp-sum ----------------
// rt=4: 64 rows/wave doubles B-reuse per LDS read (LDS port is the
// occupancy-invariant serializer; halving per-CU B traffic is the lever
// R1/R4's null results pointed to). 128-thr blocks (2 waves), 128 rows/
// block, 2 col-splits -> grid 256 = 1 block/CU. __launch_bounds__(128,1)
// gives the full 512-VGPR file so af[4][16] (256 VGPRs) does NOT spill
// (R2's rt=4 failure mode). Counted-vmcnt double-buffer as in R4.
template <bool USE_XN>
__global__ __launch_bounds__(128, 1) void k_gemm(
    const float* __restrict__ x, const ushort_t* __restrict__ xn,
    const ushort_t* __restrict__ mn, const float* __restrict__ nx,
    const float* __restrict__ simpos, const float* __restrict__ wptr,
    const float* __restrict__ bptr, float* __restrict__ ps) {
  __shared__ ushort_t bs[2][CHUNK * LDB];  // 66.5 KB
  const int tid = threadIdx.x;
  const int wid = tid >> 6, lane = tid & 63;
  const int cL = lane & 15, quad = lane >> 4;
  const int bid = (int)blockIdx.x;
  const int rb = bid & 127, cb = bid >> 7;  // bid, bid+128 share XCD (128%8==0)
  const int r0 = rb * 128, cbase = cb * 512;
  const float wp = softplusf(wptr[0]), bv = bptr[0];
  const int row0w = r0 + wid * 64;

  // stage chunk 0 first so its L2 latency overlaps the A-fragment loads
  {
    const ushort_t* gsrc = mn + (size_t)cbase * DD;
#pragma unroll
    for (int t = 0; t < 16; ++t) {
      const int rr = wid + t * 2;
      async16(&bs[0][rr * LDB + lane * 8], gsrc + (size_t)rr * DD + lane * 8);
    }
  }

  short8 af[4][16];
  int jw[4];
  float sp[4][4], sacc[4][4];
#pragma unroll
  for (int rt = 0; rt < 4; ++rt) {
    jw[rt] = (row0w + rt * 16) >> 4;
    if (USE_XN) {
      const short8* xw = (const short8*)xn + (size_t)jw[rt] * 1024;
#pragma unroll
      for (int kc = 0; kc < 16; ++kc) af[rt][kc] = xw[kc * 64 + lane];
    } else {
      const int row = row0w + rt * 16 + cL;
      const float* xr = x + (size_t)row * DD;
      const float invn = 1.0f / nx[row];
#pragma unroll
      for (int kc = 0; kc < 16; ++kc) {
        const int k0 = kc * 32 + quad * 8;
        float4 p = *(const float4*)(xr + k0);
        float4 q = *(const float4*)(xr + k0 + 4);
        short8 v;
        v[0] = f2bf(p.x * invn); v[1] = f2bf(p.y * invn);
        v[2] = f2bf(p.z * invn); v[3] = f2bf(p.w * invn);
        v[4] = f2bf(q.x * invn); v[5] = f2bf(q.y * invn);
        v[6] = f2bf(q.z * invn); v[7] = f2bf(q.w * invn);
        af[rt][kc] = v;
      }
    }
#pragma unroll
    for (int r = 0; r < 4; ++r) {
      sp[rt][r] = simpos[row0w + rt * 16 + quad * 4 + r];
      sacc[rt][r] = 0.f;
    }
  }

#pragma unroll
  for (int cc = 0; cc < NCHUNK; ++cc) {
    if (cc < NCHUNK - 1) {
      const ushort_t* gsrc = mn + (size_t)(cbase + (cc + 1) * CHUNK) * DD;
      ushort_t* dst = bs[(cc + 1) & 1];
#pragma unroll
      for (int t = 0; t < 16; ++t) {
        const int rr = wid + t * 2;
        async16(&dst[rr * LDB + lane * 8], gsrc + (size_t)rr * DD + lane * 8);
      }
      SCHED0();
      asm volatile("s_waitcnt vmcnt(16)" ::: "memory");
    } else {
      asm volatile("s_waitcnt vmcnt(0)" ::: "memory");
    }
    SCHED0();
    SBAR();   // all waves' chunk-cc loads have landed
    SCHED0();

    const ushort_t* B = bs[cc & 1];
    f32x4 acc[4][2];
#pragma unroll
    for (int rt = 0; rt < 4; ++rt)
#pragma unroll
      for (int f = 0; f < 2; ++f) acc[rt][f] = (f32x4){0.f, 0.f, 0.f, 0.f};
#pragma unroll
    for (int kc = 0; kc < 16; ++kc) {
      short8 bfr[2];
#pragma unroll
      for (int f = 0; f < 2; ++f)
        bfr[f] = *(const short8*)&B[(f * 16 + cL) * LDB + kc * 32 + quad * 8];
#pragma unroll
      for (int rt = 0; rt < 4; ++rt)
#pragma unroll
        for (int f = 0; f < 2; ++f)
          acc[rt][f] = __builtin_amdgcn_mfma_f32_16x16x32_bf16(
              af[rt][kc], bfr[f], acc[rt][f], 0, 0, 0);
    }
    const int c0 = cbase + cc * CHUNK;
#pragma unroll
    for (int rt = 0; rt < 4; ++rt)
#pragma unroll
      for (int f = 0; f < 2; ++f) {
        const int cg = c0 + f * 16 + cL;
        const bool diag = (cg == jw[rt]);
#pragma unroll
        for (int r = 0; r < 4; ++r) {
          const float sim = diag ? sp[rt][r] : acc[rt][f][r];
          sacc[rt][r] += __expf(fmaf(wp, sim, bv));
        }
      }
    if (cc < NCHUNK - 1) {
      SCHED0();
      SBAR();   // all waves done reading bs[cc&1]
      SCHED0();
    }
  }

#pragma unroll
  for (int rt = 0; rt < 4; ++rt)
#pragma unroll
    for (int r = 0; r < 4; ++r) {
      float v = sacc[rt][r];
#pragma unroll
      for (int off = 1; off < 16; off <<= 1) v += __shfl_xor(v, off, 64);
      if (cL == 0)
        ps[(size_t)(row0w + rt * 16 + quad * 4 + r) * 2 + cb] = v;
    }
}

// ---------------- Kernel 3: fused per-row loss + full reduce ----------------
__global__ __launch_bounds__(1024) void k_loss(
    const float* __restrict__ ps, const float* __restrict__ simpos,
    const float* __restrict__ wptr, const float* __restrict__ bptr,
    float* __restrict__ out) {
  __shared__ float red[16];
  const int tid = threadIdx.x;
  const float wp = softplusf(wptr[0]), bv = bptr[0];
  float acc = 0.f;
#pragma unroll
  for (int i = 0; i < RR / 1024; ++i) {
    const int row = i * 1024 + tid;
    const float2 v = ((const float2*)ps)[row];
    acc += logf(v.x + v.y) - fmaf(wp, simpos[row], bv);
  }
#pragma unroll
  for (int off = 32; off > 0; off >>= 1) acc += __shfl_xor(acc, off, 64);
  if ((tid & 63) == 0) red[tid >> 6] = acc;
  __syncthreads();
  if (tid < 64) {
    float v = (tid < 16) ? red[tid] : 0.f;
#pragma unroll
    for (int off = 8; off > 0; off >>= 1) v += __shfl_xor(v, off, 64);
    if (tid == 0) out[0] = v * (1.0f / RR);
  }
}

extern "C" void kernel_launch(void* const* d_in, const int* in_sizes, int n_in,
                              void* d_out, int out_size, void* d_ws, size_t ws_size,
                              hipStream_t stream) {
  const float* x = (const float*)d_in[0];
  const float* w = (const float*)d_in[1];
  const float* b = (const float*)d_in[2];
  float* out = (float*)d_out;

  const size_t xn_bytes = (size_t)RR * DD * 2;  // 16 MB
  const size_t rest = (size_t)CC * DD * 2 + (size_t)RR * 4 * 2 +
                      (size_t)RR * 2 * 4;
  const bool use_xn = ws_size >= xn_bytes + rest + 256;

  char* base = (char*)d_ws;
  ushort_t* xn = use_xn ? (ushort_t*)base : nullptr;
  char* p = base + (use_xn ? xn_bytes : 0);
  ushort_t* mn = (ushort_t*)p;  p += (size_t)CC * DD * 2;
  float* nx     = (float*)p;    p += (size_t)RR * 4;
  float* simpos = (float*)p;    p += (size_t)RR * 4;
  float* ps     = (float*)p;    // RR*2 floats (2 col-split partials per row)

  k_pre<<<CC, 256, 0, stream>>>(x, mn, nx, simpos, xn);
  if (use_xn)
    k_gemm<true><<<256, 128, 0, stream>>>(x, xn, mn, nx, simpos, w, b, ps);
  else
    k_gemm<false><<<256, 128, 0, stream>>>(x, xn, mn, nx, simpos, w, b, ps);
  k_loss<<<1, 1024, 0, stream>>>(ps, simpos, w, b, out);
}

// Round 7
// 110.088 us; speedup vs baseline: 1.2520x; 1.2520x over previous
//
#include <hip/hip_runtime.h>
#include <math.h>

#define CC 1024
#define SS 16
#define DD 512
#define RR (CC*SS)
#define EPSV 1e-8f
#define LDB 520    // B-tile row stride (shorts): bank-floor b128 reads
#define LDX 516    // k_pre LDS row stride (floats)
#define CHUNK 32   // cols per double-buffer half: 2*32*520*2 = 66.5 KB
#define NCHUNK 16  // 512 cols / 32

typedef __attribute__((ext_vector_type(8))) short short8;
typedef __attribute__((ext_vector_type(4))) float f32x4;
typedef unsigned short ushort_t;

__device__ __forceinline__ unsigned short f2bf(float f) {
  unsigned u = __float_as_uint(f);
  u += 0x7fffu + ((u >> 16) & 1u);  // RNE
  return (unsigned short)(u >> 16);
}

__device__ __forceinline__ void async16(void* l, const void* g) {
  __builtin_amdgcn_global_load_lds(
      (const __attribute__((address_space(1))) void*)g,
      (__attribute__((address_space(3))) void*)l, 16, 0, 0);
}

__device__ __forceinline__ float softplusf(float v) {
  return (v > 20.f) ? v : log1pf(expf(v));
}

#define SBAR()   __builtin_amdgcn_s_barrier()
#define SCHED0() __builtin_amdgcn_sched_barrier(0)

// ---------------- Kernel 1: per-class precompute ----------------
// (identical to round-5 best) xn written in MFMA-FRAGMENT ORDER: 16B
// units [class][kc][quad][cL]; k_gemm loads each A-fragment as ONE
// coalesced 1KB wave read.
__global__ __launch_bounds__(256) void k_pre(
    const float* __restrict__ x, ushort_t* __restrict__ mn,
    float* __restrict__ nx, float* __restrict__ simpos,
    ushort_t* __restrict__ xn) {
  __shared__ float xs[SS * LDX];
  __shared__ float sums[DD];
  __shared__ float red[4];
  __shared__ float snm;
  __shared__ float rinv[SS];
  const int j = blockIdx.x, tid = threadIdx.x;
  const int wid = tid >> 6, lane = tid & 63;
  const float4* xj = (const float4*)(x + (size_t)j * SS * DD);
#pragma unroll
  for (int t = 0; t < 8; ++t) {
    const int idx = tid + t * 256;          // 2048 float4 units
    const int row = idx >> 7, d4 = idx & 127;
    *(float4*)(xs + row * LDX + d4 * 4) = xj[idx];
  }
  __syncthreads();

  // column sums (each thread owns a float2 column pair, kept in regs)
  float sx = 0.f, sy = 0.f;
#pragma unroll
  for (int i = 0; i < SS; ++i) {
    float2 v = *(const float2*)(xs + i * LDX + tid * 2);
    sx += v.x; sy += v.y;
  }
  ((float2*)sums)[tid] = make_float2(sx, sy);
  const float mxs = sx * (1.0f / SS), mys = sy * (1.0f / SS);
  float m2 = mxs * mxs + mys * mys;
#pragma unroll
  for (int off = 32; off > 0; off >>= 1) m2 += __shfl_xor(m2, off, 64);
  if (lane == 0) red[wid] = m2;
  __syncthreads();
  if (tid == 0) snm = sqrtf(red[0] + red[1] + red[2] + red[3]);
  __syncthreads();
  const float inm = (1.0f / SS) / snm;
  {
    unsigned lo = f2bf(sx * inm), hi = f2bf(sy * inm);
    ((unsigned*)(mn + (size_t)j * DD))[tid] = lo | (hi << 16);
  }

  // per-row norms: one 16-lane group per row, all 16 rows parallel
  {
    const int g = tid >> 4, l16 = tid & 15;
    float nx2 = 0.f, dxs = 0.f, t2 = 0.f;
    const float2* xr2 = (const float2*)(xs + g * LDX);
    const float2* sm2 = (const float2*)sums;
#pragma unroll
    for (int t = 0; t < 16; ++t) {
      float2 xv = xr2[l16 + t * 16];
      float2 sc = sm2[l16 + t * 16];
      nx2 = fmaf(xv.x, xv.x, fmaf(xv.y, xv.y, nx2));
      dxs = fmaf(xv.x, sc.x, fmaf(xv.y, sc.y, dxs));
      float tx = sc.x - xv.x, ty = sc.y - xv.y;
      t2 = fmaf(tx, tx, fmaf(ty, ty, t2));
    }
#pragma unroll
    for (int off = 1; off < 16; off <<= 1) {
      nx2 += __shfl_xor(nx2, off, 64);
      dxs += __shfl_xor(dxs, off, 64);
      t2  += __shfl_xor(t2,  off, 64);
    }
    if (l16 == 0) {
      float nxv = sqrtf(nx2);
      float tn  = sqrtf(t2);
      float num = (dxs - nx2) * (1.0f / (SS - 1));
      float den = fmaxf(nxv * tn * (1.0f / (SS - 1)), EPSV);
      nx[j * SS + g] = nxv;
      rinv[g] = 1.0f / nxv;
      simpos[j * SS + g] = num / den;
    }
  }
  __syncthreads();
  if (xn) {
    uint4* dst = (uint4*)xn + (size_t)j * 1024;  // 1024 16B units per class
#pragma unroll
    for (int t = 0; t < 4; ++t) {
      const int idxu = tid + t * 256;
      const int kc = idxu >> 6, quad = (idxu >> 4) & 3, cL = idxu & 15;
      const float* s = xs + cL * LDX + kc * 32 + quad * 8;
      const float4 a = *(const float4*)s;
      const float4 b2 = *(const float4*)(s + 4);
      const float ri = rinv[cL];
      uint4 o;
      o.x = (unsigned)f2bf(a.x * ri) | ((unsigned)f2bf(a.y * ri) << 16);
      o.y = (unsigned)f2bf(a.z * ri) | ((unsigned)f2bf(a.w * ri) << 16);
      o.z = (unsigned)f2bf(b2.x * ri) | ((unsigned)f2bf(b2.y * ri) << 16);
      o.w = (unsigned)f2bf(b2.z * ri) | ((unsigned)f2bf(b2.w * ri) << 16);
      dst[idxu] = o;
    }
  }
}

// ---------------- Kernel 2: MFMA GEMM + fused exp-sum ----------------
// (identical to round-5 best: rt=2, 512 blocks x 128 thr, 2 col-splits,
// CHUNK=32 counted-vmcnt double-buffer, fragment-ordered A loads)
template <bool USE_XN>
__global__ __launch_bounds__(128, 2) void k_gemm(
    const float* __restrict__ x, const ushort_t* __restrict__ xn,
    const ushort_t* __restrict__ mn, const float* __restrict__ nx,
    const float* __restrict__ simpos, const float* __restrict__ wptr,
    const float* __restrict__ bptr, float* __restrict__ ps) {
  __shared__ ushort_t bs[2][CHUNK * LDB];  // 66.5 KB
  const int tid = threadIdx.x;
  const int wid = tid >> 6, lane = tid & 63;
  const int cL = lane & 15, quad = lane >> 4;
  const int bid = (int)blockIdx.x;
  const int rb = bid & 255, cb = bid >> 8;  // bid, bid+256 share XCD
  const int r0 = rb * 64, cbase = cb * 512;
  const float wp = softplusf(wptr[0]), bv = bptr[0];
  const int row0w = r0 + wid * 32;

  // stage chunk 0 first so its L2 latency overlaps the A-fragment loads
  {
    const ushort_t* gsrc = mn + (size_t)cbase * DD;
#pragma unroll
    for (int t = 0; t < 16; ++t) {
      const int rr = wid + t * 2;
      async16(&bs[0][rr * LDB + lane * 8], gsrc + (size_t)rr * DD + lane * 8);
    }
  }

  short8 af[2][16];
  int jw[2];
  float sp[2][4], sacc[2][4];
#pragma unroll
  for (int rt = 0; rt < 2; ++rt) {
    jw[rt] = (row0w + rt * 16) >> 4;
    if (USE_XN) {
      const short8* xw = (const short8*)xn + (size_t)jw[rt] * 1024;
#pragma unroll
      for (int kc = 0; kc < 16; ++kc) af[rt][kc] = xw[kc * 64 + lane];
    } else {
      const int row = row0w + rt * 16 + cL;
      const float* xr = x + (size_t)row * DD;
      const float invn = 1.0f / nx[row];
#pragma unroll
      for (int kc = 0; kc < 16; ++kc) {
        const int k0 = kc * 32 + quad * 8;
        float4 p = *(const float4*)(xr + k0);
        float4 q = *(const float4*)(xr + k0 + 4);
        short8 v;
        v[0] = f2bf(p.x * invn); v[1] = f2bf(p.y * invn);
        v[2] = f2bf(p.z * invn); v[3] = f2bf(p.w * invn);
        v[4] = f2bf(q.x * invn); v[5] = f2bf(q.y * invn);
        v[6] = f2bf(q.z * invn); v[7] = f2bf(q.w * invn);
        af[rt][kc] = v;
      }
    }
#pragma unroll
    for (int r = 0; r < 4; ++r) {
      sp[rt][r] = simpos[row0w + rt * 16 + quad * 4 + r];
      sacc[rt][r] = 0.f;
    }
  }

#pragma unroll
  for (int cc = 0; cc < NCHUNK; ++cc) {
    if (cc < NCHUNK - 1) {
      const ushort_t* gsrc = mn + (size_t)(cbase + (cc + 1) * CHUNK) * DD;
      ushort_t* dst = bs[(cc + 1) & 1];
#pragma unroll
      for (int t = 0; t < 16; ++t) {
        const int rr = wid + t * 2;
        async16(&dst[rr * LDB + lane * 8], gsrc + (size_t)rr * DD + lane * 8);
      }
      SCHED0();
      asm volatile("s_waitcnt vmcnt(16)" ::: "memory");
    } else {
      asm volatile("s_waitcnt vmcnt(0)" ::: "memory");
    }
    SCHED0();
    SBAR();   // all waves' chunk-cc loads have landed
    SCHED0();

    const ushort_t* B = bs[cc & 1];
    f32x4 acc[2][2];
#pragma unroll
    for (int rt = 0; rt < 2; ++rt)
#pragma unroll
      for (int f = 0; f < 2; ++f) acc[rt][f] = (f32x4){0.f, 0.f, 0.f, 0.f};
#pragma unroll
    for (int kc = 0; kc < 16; ++kc) {
      short8 bfr[2];
#pragma unroll
      for (int f = 0; f < 2; ++f)
        bfr[f] = *(const short8*)&B[(f * 16 + cL) * LDB + kc * 32 + quad * 8];
#pragma unroll
      for (int rt = 0; rt < 2; ++rt)
#pragma unroll
        for (int f = 0; f < 2; ++f)
          acc[rt][f] = __builtin_amdgcn_mfma_f32_16x16x32_bf16(
              af[rt][kc], bfr[f], acc[rt][f], 0, 0, 0);
    }
    const int c0 = cbase + cc * CHUNK;
#pragma unroll
    for (int rt = 0; rt < 2; ++rt)
#pragma unroll
      for (int f = 0; f < 2; ++f) {
        const int cg = c0 + f * 16 + cL;
        const bool diag = (cg == jw[rt]);
#pragma unroll
        for (int r = 0; r < 4; ++r) {
          const float sim = diag ? sp[rt][r] : acc[rt][f][r];
          sacc[rt][r] += __expf(fmaf(wp, sim, bv));
        }
      }
    if (cc < NCHUNK - 1) {
      SCHED0();
      SBAR();   // all waves done reading bs[cc&1]
      SCHED0();
    }
  }

#pragma unroll
  for (int rt = 0; rt < 2; ++rt)
#pragma unroll
    for (int r = 0; r < 4; ++r) {
      float v = sacc[rt][r];
#pragma unroll
      for (int off = 1; off < 16; off <<= 1) v += __shfl_xor(v, off, 64);
      if (cL == 0)
        ps[(size_t)(row0w + rt * 16 + quad * 4 + r) * 2 + cb] = v;
    }
}

// ---------------- Kernel 3: per-row loss + parallel block reduce ----------------
// R3's single-block k_loss was a 1-CU kernel reading 192 KB at one CU's
// HBM share (~8-12 us). Restore the 64-block parallel reduce + tiny
// finisher (R1 structure, ~2-4 us total).
__global__ __launch_bounds__(256) void k_combine(
    const float* __restrict__ ps, const float* __restrict__ simpos,
    const float* __restrict__ wptr, const float* __restrict__ bptr,
    float* __restrict__ p2) {
  __shared__ float red[4];
  const int tid = threadIdx.x;
  const int row = blockIdx.x * 256 + tid;
  const float wp = softplusf(wptr[0]), bv = bptr[0];
  const float2 v2 = ((const float2*)ps)[row];
  float v = logf(v2.x + v2.y) - fmaf(wp, simpos[row], bv);
#pragma unroll
  for (int off = 32; off > 0; off >>= 1) v += __shfl_xor(v, off, 64);
  if ((tid & 63) == 0) red[tid >> 6] = v;
  __syncthreads();
  if (tid == 0) p2[blockIdx.x] = red[0] + red[1] + red[2] + red[3];
}

__global__ __launch_bounds__(64) void k_fin(const float* __restrict__ p2,
                                            float* __restrict__ out) {
  const int tid = threadIdx.x;
  float v = p2[tid];
#pragma unroll
  for (int off = 32; off > 0; off >>= 1) v += __shfl_xor(v, off, 64);
  if (tid == 0) out[0] = v * (1.0f / RR);
}

extern "C" void kernel_launch(void* const* d_in, const int* in_sizes, int n_in,
                              void* d_out, int out_size, void* d_ws, size_t ws_size,
                              hipStream_t stream) {
  const float* x = (const float*)d_in[0];
  const float* w = (const float*)d_in[1];
  const float* b = (const float*)d_in[2];
  float* out = (float*)d_out;

  const size_t xn_bytes = (size_t)RR * DD * 2;  // 16 MB
  const size_t rest = (size_t)CC * DD * 2 + (size_t)RR * 4 * 2 +
                      (size_t)RR * 2 * 4 + 64 * 4;
  const bool use_xn = ws_size >= xn_bytes + rest + 256;

  char* base = (char*)d_ws;
  ushort_t* xn = use_xn ? (ushort_t*)base : nullptr;
  char* p = base + (use_xn ? xn_bytes : 0);
  ushort_t* mn = (ushort_t*)p;  p += (size_t)CC * DD * 2;
  float* nx     = (float*)p;    p += (size_t)RR * 4;
  float* simpos = (float*)p;    p += (size_t)RR * 4;
  float* ps     = (float*)p;    p += (size_t)RR * 2 * 4;
  float* p2     = (float*)p;

  k_pre<<<CC, 256, 0, stream>>>(x, mn, nx, simpos, xn);
  if (use_xn)
    k_gemm<true><<<512, 128, 0, stream>>>(x, xn, mn, nx, simpos, w, b, ps);
  else
    k_gemm<false><<<512, 128, 0, stream>>>(x, xn, mn, nx, simpos, w, b, ps);
  k_combine<<<RR / 256, 256, 0, stream>>>(ps, simpos, w, b, p2);
  k_fin<<<1, 64, 0, stream>>>(p2, out);
}